// Round 2
// baseline (443.816 us; speedup 1.0000x reference)
//
#include <hip/hip_runtime.h>
#include <hip/hip_bf16.h>
#include <math.h>

// Problem constants (fixed by reference)
#define BATCH 4096
#define LNUM  4
#define NEIGH 32
#define FEAT  256
#define EMB   128

// ---------------------------------------------------------------------------
// K1: gather + sum over neighbors, via async global->LDS DMA.
// S[(b*L+l)*256 + f] = sum_j features[neighs[b,l,j], f]
// Grid: 4096 blocks x 256 threads. Wave w handles layer w.
// Per wave: 32 neighbor rows in 4 chunks of 8; each chunk: 8x
// global_load_lds_dwordx4 (1 KB/row, zero VGPR data traffic), wait, sum from
// LDS with ds_read_b128. LDS 32 KB/block -> 5 blocks/CU -> 20 waves/CU; up to
// 8 KB per wave in flight => latency fully hidden, BW-bound.
// ---------------------------------------------------------------------------
__global__ __launch_bounds__(256) void k1_gather_sum(
    const int* __restrict__ neighs, const float* __restrict__ features,
    float* __restrict__ S) {
  __shared__ float buf[4][8][FEAT];  // 4 waves x 8 rows x 1 KB = 32 KB
  int b = blockIdx.x;
  int w = threadIdx.x >> 6;   // wave index = layer
  int lane = threadIdx.x & 63;
  const int* nbr = neighs + ((size_t)b * LNUM + w) * NEIGH;
  int myn = nbr[lane & 31];   // lanes 0..31 hold the 32 indices
  float ax = 0.f, ay = 0.f, az = 0.f, aw = 0.f;
#pragma unroll
  for (int c = 0; c < 4; ++c) {
#pragma unroll
    for (int j = 0; j < 8; ++j) {
      int n = __builtin_amdgcn_readlane(myn, c * 8 + j);  // SGPR index
      const float* gp = features + (size_t)n * FEAT + lane * 4;
      __builtin_amdgcn_global_load_lds(
          (const __attribute__((address_space(1))) void*)gp,
          (__attribute__((address_space(3))) void*)&buf[w][j][lane * 4],
          16, 0, 0);
    }
    asm volatile("s_waitcnt vmcnt(0)" ::: "memory");
#pragma unroll
    for (int j = 0; j < 8; ++j) {
      float4 v = *(const float4*)&buf[w][j][lane * 4];
      ax += v.x; ay += v.y; az += v.z; aw += v.w;
    }
    // ensure ds_reads of this chunk are drained before next chunk's DMA
    // overwrites the same LDS rows (DMA writes are ordered by vmcnt only)
    asm volatile("s_waitcnt lgkmcnt(0)" ::: "memory");
  }
  float4 o = make_float4(ax, ay, az, aw);
  ((float4*)S)[((size_t)b * LNUM + w) * (FEAT / 4) + lane] = o;
}

// ---------------------------------------------------------------------------
// K2: H[(b*L+l)*128 + m] = sum_f S[(b*L+l)*256+f] * W[l*F*M + f*M + m]
// Grid: (4096/32, 4), block 128. Tile: 32 rows x 128 cols, K=256.
// ---------------------------------------------------------------------------
__global__ __launch_bounds__(128) void k2_h(
    const float* __restrict__ S, const float* __restrict__ W,
    float* __restrict__ H) {
  __shared__ float sS[32 * FEAT];  // 32 KB
  int l = blockIdx.y;
  int b0 = blockIdx.x * 32;
  const float* Wl = W + (size_t)l * FEAT * EMB;
  for (int i = threadIdx.x; i < 32 * (FEAT / 4); i += 128) {
    int r = i >> 6;
    int c = i & 63;
    ((float4*)sS)[i] =
        ((const float4*)S)[((size_t)(b0 + r) * LNUM + l) * (FEAT / 4) + c];
  }
  __syncthreads();
  int tx = threadIdx.x & 31;
  int ty = threadIdx.x >> 5;
  float acc[8][4] = {};
#pragma unroll 4
  for (int k = 0; k < FEAT; ++k) {
    float4 w = ((const float4*)(Wl + (size_t)k * EMB))[tx];
#pragma unroll
    for (int r = 0; r < 8; ++r) {
      float s = sS[(ty * 8 + r) * FEAT + k];
      acc[r][0] += s * w.x; acc[r][1] += s * w.y;
      acc[r][2] += s * w.z; acc[r][3] += s * w.w;
    }
  }
#pragma unroll
  for (int r = 0; r < 8; ++r) {
    int b = b0 + ty * 8 + r;
    float4 o = make_float4(acc[r][0], acc[r][1], acc[r][2], acc[r][3]);
    ((float4*)H)[((size_t)b * LNUM + l) * (EMB / 4) + tx] = o;
  }
}

// ---------------------------------------------------------------------------
// K3: scores[row] = sum_c tanh( sum_k H[row,k]*Ws1[k,c] ) * Ws2[c]
// ---------------------------------------------------------------------------
__global__ __launch_bounds__(128) void k3_scores(
    const float* __restrict__ H, const float* __restrict__ Ws1,
    const float* __restrict__ Ws2, float* __restrict__ scores) {
  __shared__ float sH[32 * EMB];  // 16 KB
  int r0 = blockIdx.x * 32;
  for (int i = threadIdx.x; i < 32 * (EMB / 4); i += 128) {
    ((float4*)sH)[i] = ((const float4*)H)[(size_t)r0 * (EMB / 4) + i];
  }
  __syncthreads();
  int tx = threadIdx.x & 31;
  int ty = threadIdx.x >> 5;
  float acc[8][4] = {};
#pragma unroll 4
  for (int k = 0; k < EMB; ++k) {
    float4 w = ((const float4*)(Ws1 + (size_t)k * EMB))[tx];
#pragma unroll
    for (int r = 0; r < 8; ++r) {
      float h = sH[(ty * 8 + r) * EMB + k];
      acc[r][0] += h * w.x; acc[r][1] += h * w.y;
      acc[r][2] += h * w.z; acc[r][3] += h * w.w;
    }
  }
  float4 w2 = ((const float4*)Ws2)[tx];
#pragma unroll
  for (int r = 0; r < 8; ++r) {
    float p = tanhf(acc[r][0]) * w2.x + tanhf(acc[r][1]) * w2.y +
              tanhf(acc[r][2]) * w2.z + tanhf(acc[r][3]) * w2.w;
#pragma unroll
    for (int m = 1; m < 32; m <<= 1) p += __shfl_xor(p, m, 64);
    if (tx == 0) scores[r0 + ty * 8 + r] = p;
  }
}

// ---------------------------------------------------------------------------
// K4: softmax over L, agg = sum_l att*H, out = agg@Wt + layer_embs gather,
//     then L2-normalize each row.
// ---------------------------------------------------------------------------
__global__ __launch_bounds__(256) void k4_out(
    const float* __restrict__ H, const float* __restrict__ scores,
    const float* __restrict__ Wt, const int* __restrict__ node_i,
    const int* __restrict__ layers, const float* __restrict__ layer_embs,
    float* __restrict__ out) {
  __shared__ float sAgg[16 * EMB];  // 8 KB
  __shared__ float sAtt[16 * LNUM];
  int b0 = blockIdx.x * 16;
  int tid = threadIdx.x;
  if (tid < 16 * LNUM) {
    int b = b0 + (tid >> 2);
    int l = tid & 3;
    float s0 = scores[b * 4 + 0], s1 = scores[b * 4 + 1];
    float s2 = scores[b * 4 + 2], s3 = scores[b * 4 + 3];
    float mx = fmaxf(fmaxf(s0, s1), fmaxf(s2, s3));
    float sum = expf(s0 - mx) + expf(s1 - mx) + expf(s2 - mx) + expf(s3 - mx);
    sAtt[tid] = expf(scores[b * 4 + l] - mx) / sum;
  }
  __syncthreads();
  for (int i = tid; i < 16 * EMB; i += 256) {
    int r = i >> 7;
    int m = i & 127;
    int b = b0 + r;
    float a = 0.f;
#pragma unroll
    for (int l = 0; l < LNUM; ++l)
      a += sAtt[r * 4 + l] * H[((size_t)b * LNUM + l) * EMB + m];
    sAgg[i] = a;
  }
  __syncthreads();
  int tx = tid & 31;
  int ty = tid >> 5;
  float acc[2][4] = {};
#pragma unroll 4
  for (int k = 0; k < EMB; ++k) {
    float4 w = ((const float4*)(Wt + (size_t)k * EMB))[tx];
#pragma unroll
    for (int r = 0; r < 2; ++r) {
      float a = sAgg[(ty * 2 + r) * EMB + k];
      acc[r][0] += a * w.x; acc[r][1] += a * w.y;
      acc[r][2] += a * w.z; acc[r][3] += a * w.w;
    }
  }
#pragma unroll
  for (int r = 0; r < 2; ++r) {
    int b = b0 + ty * 2 + r;
    int node = node_i[b];
    int lay = layers[b];
    float4 e =
        ((const float4*)(layer_embs + ((size_t)node * LNUM + lay) * EMB))[tx];
    acc[r][0] += e.x; acc[r][1] += e.y; acc[r][2] += e.z; acc[r][3] += e.w;
    float ss = acc[r][0] * acc[r][0] + acc[r][1] * acc[r][1] +
               acc[r][2] * acc[r][2] + acc[r][3] * acc[r][3];
#pragma unroll
    for (int m = 1; m < 32; m <<= 1) ss += __shfl_xor(ss, m, 64);
    float inv = 1.0f / fmaxf(sqrtf(ss), 1e-12f);
    float4 o = make_float4(acc[r][0] * inv, acc[r][1] * inv, acc[r][2] * inv,
                           acc[r][3] * inv);
    ((float4*)out)[(size_t)b * (EMB / 4) + tx] = o;
  }
}

extern "C" void kernel_launch(void* const* d_in, const int* in_sizes, int n_in,
                              void* d_out, int out_size, void* d_ws,
                              size_t ws_size, hipStream_t stream) {
  const int* layers = (const int*)d_in[0];
  const int* node_i = (const int*)d_in[1];
  const int* neighs = (const int*)d_in[2];
  const float* features = (const float*)d_in[3];
  const float* layer_embs = (const float*)d_in[4];
  const float* neigh_emb_trans = (const float*)d_in[5];
  const float* trans_weights = (const float*)d_in[6];
  const float* trans_weights_s1 = (const float*)d_in[7];
  const float* trans_weights_s2 = (const float*)d_in[8];
  float* out = (float*)d_out;

  // workspace layout (floats): S [16384*256] | H [16384*128] | scores [16384]
  float* S = (float*)d_ws;
  float* H = S + (size_t)BATCH * LNUM * FEAT;
  float* scores = H + (size_t)BATCH * LNUM * EMB;

  k1_gather_sum<<<dim3(BATCH), 256, 0, stream>>>(neighs, features, S);
  k2_h<<<dim3(BATCH / 32, LNUM), 128, 0, stream>>>(S, neigh_emb_trans, H);
  k3_scores<<<dim3(BATCH * LNUM / 32), 128, 0, stream>>>(
      H, trans_weights_s1, trans_weights_s2, scores);
  k4_out<<<dim3(BATCH / 16), 256, 0, stream>>>(H, scores, trans_weights,
                                               node_i, layers, layer_embs, out);
}

// Round 3
// 404.656 us; speedup vs baseline: 1.0968x; 1.0968x over previous
//
#include <hip/hip_runtime.h>
#include <hip/hip_bf16.h>
#include <math.h>

// Problem constants (fixed by reference)
#define BATCH 4096
#define LNUM  4
#define NEIGH 32
#define FEAT  256
#define EMB   128

#define B_TILE 8                 // batches per block
#define ROWS   (B_TILE * LNUM)   // 32 (b,l) rows per block

// ---------------------------------------------------------------------------
// Fully fused kernel: one block handles 8 batches end-to-end.
//  P1 gather+sum:  sS[r][0:256] = sum_j features[neighs[b,l,j]]   (wave-split)
//  P2 h-GEMM:      sH[r][0:128] = sS[r] @ W[layer(r)]             (wave=layer)
//  P3 scores:      sc[r] = tanh(sH[r] @ Ws1) @ Ws2                (wave-split)
//  P4 softmax+agg+out GEMM+residual+L2 normalize -> out
// LDS: sS 32KB + sH 16KB + sc 128B = 48.1KB (sAgg overlays dead sS)
// -> 3 blocks/CU. Grid 512 = 2 resident blocks/CU.
// ---------------------------------------------------------------------------
__global__ __launch_bounds__(256) void fused_liamne(
    const int* __restrict__ layers, const int* __restrict__ node_i,
    const int* __restrict__ neighs, const float* __restrict__ features,
    const float* __restrict__ layer_embs, const float* __restrict__ W,
    const float* __restrict__ Wt, const float* __restrict__ Ws1,
    const float* __restrict__ Ws2, float* __restrict__ out) {
  __shared__ float sS[ROWS][FEAT];   // 32 KB; reused as sAgg in P4
  __shared__ float sH[ROWS][EMB];    // 16 KB
  __shared__ float sc[ROWS];

  int b0 = blockIdx.x * B_TILE;
  int tid = threadIdx.x;
  int w = tid >> 6;       // wave index 0..3
  int lane = tid & 63;

  // ---- Phase 1: gather + neighbor-sum into sS --------------------------
  // wave w handles rows r = w*8 .. w*8+7; each row: 32 coalesced 1KB loads.
#pragma unroll
  for (int i = 0; i < 8; ++i) {
    int r = w * 8 + i;
    int lb = r >> 2, l = r & 3;
    const int* nbr = neighs + ((size_t)(b0 + lb) * LNUM + l) * NEIGH;
    int myn = nbr[lane & 31];  // lanes 0..31 hold the 32 indices (dup in hi)
    float ax = 0.f, ay = 0.f, az = 0.f, aw = 0.f;
#pragma unroll 8
    for (int j = 0; j < NEIGH; ++j) {
      int n = __shfl(myn, j, 64);
      float4 v = ((const float4*)(features + (size_t)n * FEAT))[lane];
      ax += v.x; ay += v.y; az += v.z; aw += v.w;
    }
    ((float4*)sS[r])[lane] = make_float4(ax, ay, az, aw);
  }
  __syncthreads();

  // ---- Phase 2: sH[r] = sS[r] @ W[l], wave w == layer w ----------------
  {
    const float* Wl = W + (size_t)w * FEAT * EMB;
    float acc[8][2] = {};
    for (int k = 0; k < FEAT; k += 4) {
      float4 s[8];
#pragma unroll
      for (int lb = 0; lb < 8; ++lb)
        s[lb] = *(const float4*)&sS[lb * 4 + w][k];  // LDS broadcast read
#pragma unroll
      for (int kk = 0; kk < 4; ++kk) {
        float2 wv = *(const float2*)&Wl[(size_t)(k + kk) * EMB + lane * 2];
#pragma unroll
        for (int lb = 0; lb < 8; ++lb) {
          float sv = ((const float*)&s[lb])[kk];
          acc[lb][0] += sv * wv.x;
          acc[lb][1] += sv * wv.y;
        }
      }
    }
#pragma unroll
    for (int lb = 0; lb < 8; ++lb)
      *(float2*)&sH[lb * 4 + w][lane * 2] = make_float2(acc[lb][0], acc[lb][1]);
  }
  __syncthreads();

  // ---- Phase 3: sc[r] = tanh(sH[r] @ Ws1) @ Ws2 ------------------------
  {
    float acc[8][2] = {};
    for (int k = 0; k < EMB; k += 4) {
      float4 h[8];
#pragma unroll
      for (int i = 0; i < 8; ++i)
        h[i] = *(const float4*)&sH[w * 8 + i][k];
#pragma unroll
      for (int kk = 0; kk < 4; ++kk) {
        float2 wv = *(const float2*)&Ws1[(size_t)(k + kk) * EMB + lane * 2];
#pragma unroll
        for (int i = 0; i < 8; ++i) {
          float hv = ((const float*)&h[i])[kk];
          acc[i][0] += hv * wv.x;
          acc[i][1] += hv * wv.y;
        }
      }
    }
    float2 w2 = *(const float2*)&Ws2[lane * 2];
#pragma unroll
    for (int i = 0; i < 8; ++i) {
      float p = tanhf(acc[i][0]) * w2.x + tanhf(acc[i][1]) * w2.y;
#pragma unroll
      for (int m = 1; m < 64; m <<= 1) p += __shfl_xor(p, m, 64);
      if (lane == 0) sc[w * 8 + i] = p;
    }
  }
  __syncthreads();

  // ---- Phase 4a: softmax + attention-weighted agg into sAgg (= sS) -----
  float* sAgg = &sS[0][0];  // B_TILE x EMB, overlays dead sS
  for (int i = tid; i < B_TILE * EMB; i += 256) {
    int lb = i >> 7, m = i & 127;
    float s0 = sc[lb * 4 + 0], s1 = sc[lb * 4 + 1];
    float s2 = sc[lb * 4 + 2], s3 = sc[lb * 4 + 3];
    float mx = fmaxf(fmaxf(s0, s1), fmaxf(s2, s3));
    float e0 = expf(s0 - mx), e1 = expf(s1 - mx);
    float e2 = expf(s2 - mx), e3 = expf(s3 - mx);
    float inv = 1.0f / (e0 + e1 + e2 + e3);
    float a = e0 * sH[lb * 4 + 0][m] + e1 * sH[lb * 4 + 1][m] +
              e2 * sH[lb * 4 + 2][m] + e3 * sH[lb * 4 + 3][m];
    sAgg[i] = a * inv;
  }
  __syncthreads();

  // ---- Phase 4b: out = normalize(agg @ Wt + layer_embs[node, layer]) ---
  {
    int g = tid >> 5;   // batch within tile
    int t = tid & 31;   // 4 output cols
    float ax = 0.f, ay = 0.f, az = 0.f, aw = 0.f;
    for (int k = 0; k < EMB; ++k) {
      float4 wv = ((const float4*)(Wt + (size_t)k * EMB))[t];
      float a = sAgg[g * EMB + k];
      ax += a * wv.x; ay += a * wv.y; az += a * wv.z; aw += a * wv.w;
    }
    int b = b0 + g;
    int node = node_i[b];
    int lay = layers[b];
    float4 e =
        ((const float4*)(layer_embs + ((size_t)node * LNUM + lay) * EMB))[t];
    ax += e.x; ay += e.y; az += e.z; aw += e.w;
    float ss = ax * ax + ay * ay + az * az + aw * aw;
#pragma unroll
    for (int m = 1; m < 32; m <<= 1) ss += __shfl_xor(ss, m, 64);
    float inv = 1.0f / fmaxf(sqrtf(ss), 1e-12f);
    ((float4*)(out + (size_t)b * EMB))[t] =
        make_float4(ax * inv, ay * inv, az * inv, aw * inv);
  }
}

extern "C" void kernel_launch(void* const* d_in, const int* in_sizes, int n_in,
                              void* d_out, int out_size, void* d_ws,
                              size_t ws_size, hipStream_t stream) {
  const int* layers = (const int*)d_in[0];
  const int* node_i = (const int*)d_in[1];
  const int* neighs = (const int*)d_in[2];
  const float* features = (const float*)d_in[3];
  const float* layer_embs = (const float*)d_in[4];
  const float* neigh_emb_trans = (const float*)d_in[5];
  const float* trans_weights = (const float*)d_in[6];
  const float* trans_weights_s1 = (const float*)d_in[7];
  const float* trans_weights_s2 = (const float*)d_in[8];
  float* out = (float*)d_out;

  fused_liamne<<<dim3(BATCH / B_TILE), 256, 0, stream>>>(
      layers, node_i, neighs, features, layer_embs, neigh_emb_trans,
      trans_weights, trans_weights_s1, trans_weights_s2, out);
}

// Round 4
// 397.883 us; speedup vs baseline: 1.1154x; 1.0170x over previous
//
#include <hip/hip_runtime.h>
#include <hip/hip_bf16.h>
#include <math.h>

// Problem constants (fixed by reference)
#define BATCH 4096
#define LNUM  4
#define NEIGH 32
#define FEAT  256
#define EMB   128

#define B_TILE 4                 // batches per block
#define ROWS   (B_TILE * LNUM)   // 16 (b,l) rows per block

// ---------------------------------------------------------------------------
// Fully fused kernel: one block handles 4 batches end-to-end.
//  P1 gather+sum:  sS[r][0:256] = sum_j features[neighs[b,l,j]]  (wave=batch)
//  P2 h-GEMM:      sH[r][0:128] = sS[r] @ W[layer(r)]            (wave=layer)
//  P3 scores:      sc[r] = tanh(sH[r] @ Ws1) @ Ws2               (wave-split)
//  P4 softmax+agg+out GEMM+residual+L2 normalize -> out          (wave=batch)
// LDS: sS 16KB + sH 8KB + sc 64B = 24.2KB -> 4 blocks/CU resident with
// __launch_bounds__(256,4); grid 1024 = all blocks resident, 16 waves/CU.
// P1 keeps 16 independent float4 loads in flight per wave (4 rows x 4 j).
// ---------------------------------------------------------------------------
__global__ __launch_bounds__(256, 4) void fused_liamne(
    const int* __restrict__ layers, const int* __restrict__ node_i,
    const int* __restrict__ neighs, const float* __restrict__ features,
    const float* __restrict__ layer_embs, const float* __restrict__ W,
    const float* __restrict__ Wt, const float* __restrict__ Ws1,
    const float* __restrict__ Ws2, float* __restrict__ out) {
  __shared__ float sS[ROWS][FEAT];   // 16 KB; reused as sAgg in P4
  __shared__ float sH[ROWS][EMB];    // 8 KB
  __shared__ float sc[ROWS];

  int b0 = blockIdx.x * B_TILE;
  int tid = threadIdx.x;
  int w = tid >> 6;       // wave index 0..3
  int lane = tid & 63;

  // ---- Phase 1: gather + neighbor-sum into sS. Wave w owns batch b0+w. ---
  {
    int nIdx[LNUM];
#pragma unroll
    for (int l = 0; l < LNUM; ++l) {
      const int* nbr = neighs + ((size_t)(b0 + w) * LNUM + l) * NEIGH;
      nIdx[l] = nbr[lane & 31];  // lanes 0..31 hold the 32 indices
    }
    const float4* f4 = (const float4*)features;
    float4 acc[LNUM];
#pragma unroll
    for (int l = 0; l < LNUM; ++l) acc[l] = make_float4(0.f, 0.f, 0.f, 0.f);
#pragma unroll
    for (int jj = 0; jj < 8; ++jj) {       // fully unrolled: constant shfl
      float4 v[LNUM][4];
#pragma unroll
      for (int l = 0; l < LNUM; ++l)
#pragma unroll
        for (int q = 0; q < 4; ++q) {
          int n = __shfl(nIdx[l], jj * 4 + q, 64);
          v[l][q] = f4[(size_t)n * (FEAT / 4) + lane];
        }
#pragma unroll
      for (int l = 0; l < LNUM; ++l)
#pragma unroll
        for (int q = 0; q < 4; ++q) {
          acc[l].x += v[l][q].x; acc[l].y += v[l][q].y;
          acc[l].z += v[l][q].z; acc[l].w += v[l][q].w;
        }
    }
#pragma unroll
    for (int l = 0; l < LNUM; ++l)
      ((float4*)sS[w * LNUM + l])[lane] = acc[l];
  }
  __syncthreads();

  // ---- Phase 2: sH[lb*4+w] = sS[lb*4+w] @ W[w], wave w == layer w --------
  {
    const float* Wl = W + (size_t)w * FEAT * EMB;
    float acc[B_TILE][2] = {};
    for (int k = 0; k < FEAT; k += 4) {
      float4 s[B_TILE];
#pragma unroll
      for (int lb = 0; lb < B_TILE; ++lb)
        s[lb] = *(const float4*)&sS[lb * LNUM + w][k];
#pragma unroll
      for (int kk = 0; kk < 4; ++kk) {
        float2 wv = *(const float2*)&Wl[(size_t)(k + kk) * EMB + lane * 2];
#pragma unroll
        for (int lb = 0; lb < B_TILE; ++lb) {
          float sv = ((const float*)&s[lb])[kk];
          acc[lb][0] += sv * wv.x;
          acc[lb][1] += sv * wv.y;
        }
      }
    }
#pragma unroll
    for (int lb = 0; lb < B_TILE; ++lb)
      *(float2*)&sH[lb * LNUM + w][lane * 2] =
          make_float2(acc[lb][0], acc[lb][1]);
  }
  __syncthreads();

  // ---- Phase 3: sc[r] = tanh(sH[r] @ Ws1) @ Ws2, rows w*4..w*4+3 ---------
  {
    float acc[4][2] = {};
    for (int k = 0; k < EMB; k += 4) {
      float4 h[4];
#pragma unroll
      for (int i = 0; i < 4; ++i)
        h[i] = *(const float4*)&sH[w * 4 + i][k];
#pragma unroll
      for (int kk = 0; kk < 4; ++kk) {
        float2 wv = *(const float2*)&Ws1[(size_t)(k + kk) * EMB + lane * 2];
#pragma unroll
        for (int i = 0; i < 4; ++i) {
          float hv = ((const float*)&h[i])[kk];
          acc[i][0] += hv * wv.x;
          acc[i][1] += hv * wv.y;
        }
      }
    }
    float2 w2 = *(const float2*)&Ws2[lane * 2];
#pragma unroll
    for (int i = 0; i < 4; ++i) {
      float p = tanhf(acc[i][0]) * w2.x + tanhf(acc[i][1]) * w2.y;
#pragma unroll
      for (int m = 1; m < 64; m <<= 1) p += __shfl_xor(p, m, 64);
      if (lane == 0) sc[w * 4 + i] = p;
    }
  }
  __syncthreads();

  // ---- Phase 4a: softmax + attention-weighted agg into sAgg (= sS) -------
  float* sAgg = &sS[0][0];  // B_TILE x EMB overlays dead sS
  for (int i = tid; i < B_TILE * EMB; i += 256) {
    int lb = i >> 7, m = i & 127;
    float s0 = sc[lb * 4 + 0], s1 = sc[lb * 4 + 1];
    float s2 = sc[lb * 4 + 2], s3 = sc[lb * 4 + 3];
    float mx = fmaxf(fmaxf(s0, s1), fmaxf(s2, s3));
    float e0 = expf(s0 - mx), e1 = expf(s1 - mx);
    float e2 = expf(s2 - mx), e3 = expf(s3 - mx);
    float inv = 1.0f / (e0 + e1 + e2 + e3);
    float a = e0 * sH[lb * 4 + 0][m] + e1 * sH[lb * 4 + 1][m] +
              e2 * sH[lb * 4 + 2][m] + e3 * sH[lb * 4 + 3][m];
    sAgg[i] = a * inv;
  }
  __syncthreads();

  // ---- Phase 4b: wave w: out[b0+w] = normalize(agg @ Wt + layer_emb) -----
  {
    float ax = 0.f, ay = 0.f;
    for (int k = 0; k < EMB; ++k) {
      float2 wv = *(const float2*)&Wt[(size_t)k * EMB + lane * 2];
      float a = sAgg[w * EMB + k];
      ax += a * wv.x;
      ay += a * wv.y;
    }
    int b = b0 + w;
    int node = node_i[b];
    int lay = layers[b];
    float2 e = *(const float2*)&layer_embs[((size_t)node * LNUM + lay) * EMB +
                                           lane * 2];
    ax += e.x;
    ay += e.y;
    float ss = ax * ax + ay * ay;
#pragma unroll
    for (int m = 1; m < 64; m <<= 1) ss += __shfl_xor(ss, m, 64);
    float inv = 1.0f / fmaxf(sqrtf(ss), 1e-12f);
    *(float2*)&out[(size_t)b * EMB + lane * 2] =
        make_float2(ax * inv, ay * inv);
  }
}

extern "C" void kernel_launch(void* const* d_in, const int* in_sizes, int n_in,
                              void* d_out, int out_size, void* d_ws,
                              size_t ws_size, hipStream_t stream) {
  const int* layers = (const int*)d_in[0];
  const int* node_i = (const int*)d_in[1];
  const int* neighs = (const int*)d_in[2];
  const float* features = (const float*)d_in[3];
  const float* layer_embs = (const float*)d_in[4];
  const float* neigh_emb_trans = (const float*)d_in[5];
  const float* trans_weights = (const float*)d_in[6];
  const float* trans_weights_s1 = (const float*)d_in[7];
  const float* trans_weights_s2 = (const float*)d_in[8];
  float* out = (float*)d_out;

  fused_liamne<<<dim3(BATCH / B_TILE), 256, 0, stream>>>(
      layers, node_i, neighs, features, layer_embs, neigh_emb_trans,
      trans_weights, trans_weights_s1, trans_weights_s2, out);
}